// Round 5
// baseline (498.892 us; speedup 1.0000x reference)
//
#include <hip/hip_runtime.h>
#include <hip/hip_bf16.h>

#define B_ 2
#define C_ 64
#define H_ 128
#define W_ 128
#define HS 64
#define WS 64
#define L_ 4096
#define S_ 4096
#define K1_ 576    // C*3*3
#define NCOL 1024  // C*4*4
#define SCALE_ 10.0f

typedef __attribute__((ext_vector_type(8))) short bf16x8;
typedef __attribute__((ext_vector_type(8))) _Float16 f16x8;
typedef __attribute__((ext_vector_type(4))) float f32x4;

// async global->LDS, 16B per lane (wave-uniform LDS base + lane*16).
__device__ __forceinline__ void async_copy16(const void* gsrc, void* ldst) {
    __builtin_amdgcn_global_load_lds(
        (__attribute__((address_space(1))) const void*)gsrc,
        (__attribute__((address_space(3))) void*)ldst, 16, 0, 0);
}

// transposed flat index within a 64x64 grid
__device__ __forceinline__ int TT(int x) { return ((x & 63) << 6) | (x >> 6); }

// generic 3-tap (d2) gather over Y with exact TT boundary semantics
__device__ __forceinline__ float diag3Y(const float* __restrict__ Y, int l, int s) {
    int tl = TT(l), ts = TT(s);
    float acc = 0.f;
#pragma unroll
    for (int d2 = -1; d2 <= 1; ++d2) {
        int p = tl + d2, q = ts + d2;
        if ((unsigned)p < 4096u && (unsigned)q < 4096u)
            acc += Y[((size_t)TT(p) << 12) + TT(q)];
    }
    return acc;
}

// ---------------- K0a: per-pixel channel sum-of-squares of downsampled bg ----------------
__global__ void k_sumsq(const float* __restrict__ bg, float* __restrict__ ssq) {
    int idx = blockIdx.x * 256 + threadIdx.x;  // B*64*64
    if (idx >= B_ * HS * WS) return;
    int pix = idx & 4095, b = idx >> 12;
    int i = pix >> 6, j = pix & 63;
    float ss = 0.f;
    for (int c = 0; c < C_; ++c) {
        float v = bg[((b * C_ + c) * H_ + 2 * i) * W_ + 2 * j];
        ss += v * v;
    }
    ssq[idx] = ss;
}

// ---------------- K0b: per-patch mask flag + 1/denom (3x3 box) ----------------
__global__ void k_patch_stats(const float* __restrict__ mask, const float* __restrict__ ssq,
                              float* __restrict__ denom_inv, float* __restrict__ maskedf) {
    int idx = blockIdx.x * 256 + threadIdx.x;  // B*L
    if (idx >= B_ * L_) return;
    int b = idx >> 12, l = idx & 4095, lh = l >> 6, lw = l & 63;
    float msum = 0.f, ss = 0.f;
    for (int di = -1; di <= 1; ++di)
        for (int dj = -1; dj <= 1; ++dj) {
            int i = lh + di, j = lw + dj;
            if (i >= 0 && i < HS && j >= 0 && j < WS) {
                msum += mask[(b * H_ + 2 * i) * W_ + 2 * j];
                ss += ssq[(b << 12) + (i << 6) + j];
            }
        }
    maskedf[idx] = (msum == 0.0f) ? 1.0f : 0.0f;
    denom_inv[idx] = 1.0f / fmaxf(sqrtf(ss), 0.001f);
}

// ---------------- K0c: fused prep: im2col (bg,fg -> fp16) + colsT (bf16), one launch ------
__global__ void k_prep(const float* __restrict__ bgb, const float* __restrict__ fgb,
                       _Float16* __restrict__ bcol, _Float16* __restrict__ fcol,
                       __hip_bfloat16* __restrict__ colsT) {
    int idx = blockIdx.x * 256 + threadIdx.x;
    if (idx < 2 * L_ * K1_) {  // im2col part (block-uniform split)
        int which = idx >= L_ * K1_;
        int id = which ? idx - L_ * K1_ : idx;
        const float* src = which ? fgb : bgb;
        _Float16* dst = which ? fcol : bcol;
        int k = id % K1_;
        int l = id / K1_;
        int c = k / 9, r = k - 9 * c;
        int r3 = r / 3;
        int di = r3 - 1, dj = r - 3 * r3 - 1;
        int i = (l >> 6) + di, j = (l & 63) + dj;
        float v = 0.f;
        if (i >= 0 && i < HS && j >= 0 && j < WS) v = src[(c * H_ + 2 * i) * W_ + 2 * j];
        dst[id] = (_Float16)v;
    } else {  // colsT part
        int id = idx - 2 * L_ * K1_;  // NCOL*L, l fastest
        int l = id & 4095, n = id >> 12;
        int kj = n & 3, ki = (n >> 2) & 3, c = n >> 4;
        int y = 2 * (l >> 6) + ki - 1, x = 2 * (l & 63) + kj - 1;
        float v = 0.f;
        if (y >= 0 && y < H_ && x >= 0 && x < W_) v = bgb[(c * H_ + y) * W_ + x];
        colsT[id] = __float2bfloat16(v);
    }
}

// ---------------- K1: scores GEMM (fp16, BK=64, XOR-8 swizzle, 2-deep pipelined) ----------
// Round-2 config (best measured: 46.5us).
__global__ __launch_bounds__(256) void k_gemm1_mfma(const _Float16* __restrict__ A,
                                                    const _Float16* __restrict__ Bm,
                                                    const float* __restrict__ dinv,
                                                    float* __restrict__ scores,
                                                    float* __restrict__ Y) {
    __shared__ __align__(16) char shraw[128 * 129 * 4];  // 66048B: 2x32KB staging / epi tile
    int t = threadIdx.x, lane = t & 63, w = t >> 6;
    int wm = w & 1, wn = w >> 1;
    int M0 = blockIdx.y * 128, N0 = blockIdx.x * 128;
    f32x4 acc[4][4] = {};

    auto stage = [&](int k0, int offh) {
        _Float16* Asb = (_Float16*)shraw + offh;
        _Float16* Bsb = Asb + 8192;
#pragma unroll
        for (int rp = 0; rp < 4; ++rp) {
            int chunk = rp * 256 + t;  // 1024 chunks of 16B
            int row = chunk >> 3;
            int kc = (chunk & 7) ^ (row & 7);  // permuted global chunk -> swizzled LDS store
            async_copy16(A + (size_t)(M0 + row) * K1_ + k0 + kc * 8, &Asb[chunk * 8]);
        }
#pragma unroll
        for (int rp = 0; rp < 4; ++rp) {
            int chunk = rp * 256 + t;
            int row = chunk >> 3;
            int kc = (chunk & 7) ^ (row & 7);
            async_copy16(Bm + (size_t)(N0 + row) * K1_ + k0 + kc * 8, &Bsb[chunk * 8]);
        }
    };

    stage(0, 0);
    int buf = 0;
    for (int k0 = 0; k0 < K1_; k0 += 64) {
        if (k0 + 64 < K1_) {
            stage(k0 + 64, (buf ^ 1) * 16384);
            asm volatile("s_waitcnt vmcnt(8)" ::: "memory");  // current tile landed
        } else {
            asm volatile("s_waitcnt vmcnt(0)" ::: "memory");
        }
        __builtin_amdgcn_s_barrier();
        _Float16* As = (_Float16*)shraw + buf * 16384;
        _Float16* Bs = As + 8192;
        int qc = lane >> 4, mr = lane & 15;
#pragma unroll
        for (int kk = 0; kk < 2; ++kk) {
            int c = kk * 4 + qc;
            f16x8 af[4], bfr[4];
#pragma unroll
            for (int i = 0; i < 4; ++i) {
                int ra = wm * 64 + i * 16 + mr;
                int rb = wn * 64 + i * 16 + mr;
                af[i] = *(const f16x8*)&As[ra * 64 + (c ^ (ra & 7)) * 8];
                bfr[i] = *(const f16x8*)&Bs[rb * 64 + (c ^ (rb & 7)) * 8];
            }
#pragma unroll
            for (int mt = 0; mt < 4; ++mt)
#pragma unroll
                for (int nt = 0; nt < 4; ++nt)
                    acc[mt][nt] = __builtin_amdgcn_mfma_f32_16x16x32_f16(af[mt], bfr[nt], acc[mt][nt], 0, 0, 0);
        }
        __builtin_amdgcn_s_barrier();  // readers done before next iter overwrites buf^1
        buf ^= 1;
    }
    int col = lane & 15, rq = (lane >> 4) * 4;
    // strip writes: raw scores on rows/cols {0,1,126,127} of this tile
#pragma unroll
    for (int mt = 0; mt < 4; ++mt)
#pragma unroll
        for (int r = 0; r < 4; ++r) {
            int ml = wm * 64 + mt * 16 + rq + r;
            bool rstrip = (ml <= 1) || (ml >= 126);
            float dv = dinv[M0 + ml];
#pragma unroll
            for (int nt = 0; nt < 4; ++nt) {
                int nl = wn * 64 + nt * 16 + col;
                bool cstrip = (nl <= 1) || (nl >= 126);
                if (rstrip || cstrip)
                    scores[((size_t)(M0 + ml) << 12) + N0 + nl] = acc[mt][nt][r] * dv;
            }
        }
    // Y interior via single full-tile LDS pass (128x129 f32)
    float* sm = (float*)shraw;
#pragma unroll
    for (int mt = 0; mt < 4; ++mt)
#pragma unroll
        for (int r = 0; r < 4; ++r) {
            int ml = wm * 64 + mt * 16 + rq + r;
            float dv = dinv[M0 + ml];
#pragma unroll
            for (int nt = 0; nt < 4; ++nt) {
                int nl = wn * 64 + nt * 16 + col;
                sm[ml * 129 + nl] = acc[mt][nt][r] * dv;
            }
        }
    __syncthreads();
    for (int e = t; e < 126 * 128; e += 256) {
        int rr = 1 + (e >> 7);
        int cc = e & 127;
        if (cc < 1 || cc > 126) continue;
        float y = sm[(rr - 1) * 129 + cc - 1] + sm[rr * 129 + cc] + sm[(rr + 1) * 129 + cc + 1];
        Y[((size_t)(M0 + rr) << 12) + N0 + cc] = y;
    }
}

// ---------------- K2a: Y boundary rows/cols from score strips (exact flat bounds) ---------
__global__ void k_pass1_edge(const float* __restrict__ scores, float* __restrict__ Y) {
    int idx = blockIdx.x * 256 + threadIdx.x;  // 2*64*4096
    int a, c;
    if (idx < 262144) {
        int ri = idx >> 12;  // 0..63
        a = (ri >> 1) * 128 + ((ri & 1) ? 127 : 0);
        c = idx & 4095;
    } else {
        int j = idx - 262144;
        int ci = j >> 12;
        c = (ci >> 1) * 128 + ((ci & 1) ? 127 : 0);
        a = j & 4095;
    }
    float acc = 0.f;
#pragma unroll
    for (int d = -1; d <= 1; ++d) {
        int aa = a + d, cc = c + d;
        if ((unsigned)aa < 4096u && (unsigned)cc < 4096u)
            acc += scores[((size_t)aa << 12) + cc];
    }
    Y[((size_t)a << 12) + c] = acc;
}

// ---------------- K2b: pass2 — 3-tap (rows +-64) + local-max exp + transpose -> softT -----
// Diagonal-major block walk + XCD-chunked swizzle (see round-0 notes); interior path
// register-prefetches all 12 float4 taps; pml/pz stored [s][lblock]; softT bf16x8 stores.
__global__ __launch_bounds__(256) void k_soft3(const float* __restrict__ Y,
                                               const float* __restrict__ maskedf,
                                               __hip_bfloat16* __restrict__ softT,
                                               float* __restrict__ pml, float* __restrict__ pz) {
    __shared__ float tile[64][65];
    __shared__ float red[16][64];
    __shared__ float mloc[64];
    int t = threadIdx.x;
    int sx4 = t & 15, lg = t >> 4;
    int bid = blockIdx.x;
    int swz = (bid & 7) * 512 + (bid >> 3);
    int dg = swz >> 6, pos = swz & 63;
    int by = pos, bx = (pos + dg) & 63;
    int s0 = bx * 64, l0 = by * 64;
    bool interior = (bx >= 1) && (bx <= 62) && (by >= 1) && (by <= 62);
    float p0 = -3.0e38f, p1 = -3.0e38f, p2 = -3.0e38f, p3 = -3.0e38f;
    if (interior) {
        float4 v[12];
        float mk[4];
#pragma unroll
        for (int j = 0; j < 4; ++j) {
            int lloc = lg + 16 * j;
#pragma unroll
            for (int d2 = 0; d2 < 3; ++d2) {
                const float* p = Y + ((size_t)(64 * (by + d2 - 1) + lloc) << 12) + 64 * (bx + d2 - 1) + 4 * sx4;
                v[j * 3 + d2] = *(const float4*)p;
            }
        }
#pragma unroll
        for (int j = 0; j < 4; ++j) mk[j] = maskedf[l0 + lg + 16 * j];
#pragma unroll
        for (int j = 0; j < 4; ++j) {
            int lloc = lg + 16 * j;
            float a0 = v[j * 3].x + v[j * 3 + 1].x + v[j * 3 + 2].x;
            float a1 = v[j * 3].y + v[j * 3 + 1].y + v[j * 3 + 2].y;
            float a2 = v[j * 3].z + v[j * 3 + 1].z + v[j * 3 + 2].z;
            float a3 = v[j * 3].w + v[j * 3 + 1].w + v[j * 3 + 2].w;
            if (mk[j] != 0.f) { a0 = -1000.f; a1 = -1000.f; a2 = -1000.f; a3 = -1000.f; }
            tile[lloc][4 * sx4 + 0] = a0;
            tile[lloc][4 * sx4 + 1] = a1;
            tile[lloc][4 * sx4 + 2] = a2;
            tile[lloc][4 * sx4 + 3] = a3;
            p0 = fmaxf(p0, a0); p1 = fmaxf(p1, a1); p2 = fmaxf(p2, a2); p3 = fmaxf(p3, a3);
        }
    } else {
#pragma unroll
        for (int j = 0; j < 4; ++j) {
            int lloc = lg + 16 * j;
            int l = l0 + lloc;
            bool mk = (maskedf[l] != 0.f);
            float a0 = mk ? -1000.f : diag3Y(Y, l, s0 + 4 * sx4 + 0);
            float a1 = mk ? -1000.f : diag3Y(Y, l, s0 + 4 * sx4 + 1);
            float a2 = mk ? -1000.f : diag3Y(Y, l, s0 + 4 * sx4 + 2);
            float a3 = mk ? -1000.f : diag3Y(Y, l, s0 + 4 * sx4 + 3);
            tile[lloc][4 * sx4 + 0] = a0;
            tile[lloc][4 * sx4 + 1] = a1;
            tile[lloc][4 * sx4 + 2] = a2;
            tile[lloc][4 * sx4 + 3] = a3;
            p0 = fmaxf(p0, a0); p1 = fmaxf(p1, a1); p2 = fmaxf(p2, a2); p3 = fmaxf(p3, a3);
        }
    }
    red[lg][4 * sx4 + 0] = p0;
    red[lg][4 * sx4 + 1] = p1;
    red[lg][4 * sx4 + 2] = p2;
    red[lg][4 * sx4 + 3] = p3;
    __syncthreads();
    if (t < 64) {
        float m = -3.0e38f;
#pragma unroll
        for (int g = 0; g < 16; ++g) m = fmaxf(m, red[g][t]);
        mloc[t] = m;
        pml[(size_t)(s0 + t) * 64 + by] = m;
    }
    __syncthreads();
    float m0 = mloc[4 * sx4 + 0], m1 = mloc[4 * sx4 + 1], m2 = mloc[4 * sx4 + 2], m3 = mloc[4 * sx4 + 3];
    float z0 = 0.f, z1 = 0.f, z2 = 0.f, z3 = 0.f;
#pragma unroll
    for (int j = 0; j < 4; ++j) {
        int lloc = lg + 16 * j;
        float e0 = __expf(SCALE_ * (tile[lloc][4 * sx4 + 0] - m0));
        float e1 = __expf(SCALE_ * (tile[lloc][4 * sx4 + 1] - m1));
        float e2 = __expf(SCALE_ * (tile[lloc][4 * sx4 + 2] - m2));
        float e3 = __expf(SCALE_ * (tile[lloc][4 * sx4 + 3] - m3));
        tile[lloc][4 * sx4 + 0] = e0;
        tile[lloc][4 * sx4 + 1] = e1;
        tile[lloc][4 * sx4 + 2] = e2;
        tile[lloc][4 * sx4 + 3] = e3;
        z0 += e0; z1 += e1; z2 += e2; z3 += e3;
    }
    red[lg][4 * sx4 + 0] = z0;
    red[lg][4 * sx4 + 1] = z1;
    red[lg][4 * sx4 + 2] = z2;
    red[lg][4 * sx4 + 3] = z3;
    __syncthreads();
    if (t < 64) {
        float zz = 0.f;
#pragma unroll
        for (int g = 0; g < 16; ++g) zz += red[g][t];
        pz[(size_t)(s0 + t) * 64 + by] = zz;
    }
#pragma unroll
    for (int pp = 0; pp < 2; ++pp) {
        int chunk = pp * 256 + t;
        int sloc = chunk >> 3, lb = (chunk & 7) * 8;
        bf16x8 o;
#pragma unroll
        for (int k = 0; k < 8; ++k) {
            __hip_bfloat16 r = __float2bfloat16(tile[lb + k][sloc]);
            o[k] = *reinterpret_cast<short*>(&r);
        }
        *(bf16x8*)(softT + ((size_t)(s0 + sloc) << 12) + l0 + lb) = o;
    }
}

// ---------------- K3: fused zfix+rescale: block per s-row --------------------------------
__global__ __launch_bounds__(256) void k_zr(const float* __restrict__ pml,
                                            const float* __restrict__ pz,
                                            __hip_bfloat16* __restrict__ softT) {
    __shared__ float facs[64];
    int t = threadIdx.x;
    int s = blockIdx.x;
    if (t < 64) {
        float pmv = pml[(size_t)s * 64 + t];
        float m = pmv;
#pragma unroll
        for (int off = 1; off < 64; off <<= 1) m = fmaxf(m, __shfl_xor(m, off));
        float fc = __expf(SCALE_ * (pmv - m));
        float g = pz[(size_t)s * 64 + t] * fc;
#pragma unroll
        for (int off = 1; off < 64; off <<= 1) g += __shfl_xor(g, off);
        facs[t] = fc * (1.0f / g);
    }
    __syncthreads();
    size_t rowbase = (size_t)s << 12;
#pragma unroll
    for (int p = 0; p < 2; ++p) {
        int chunk = t + p * 256;
        float f = facs[chunk >> 3];
        bf16x8 v = *(const bf16x8*)(softT + rowbase + chunk * 8);
        bf16x8 o;
#pragma unroll
        for (int k = 0; k < 8; ++k) {
            unsigned short us = (unsigned short)v[k];
            float x = __uint_as_float((unsigned)us << 16) * f;
            __hip_bfloat16 r = __float2bfloat16(x);
            o[k] = *reinterpret_cast<short*>(&r);
        }
        *(bf16x8*)(softT + rowbase + chunk * 8) = o;
    }
}

// ---------------- K6: deconv GEMM, split-K z=4, BM=128 BN=128 BK=64, XOR-8 swizzle --------
// Round-5: keep BN=128 (32 MFMA per 32KB staged per K-step) but restore TLP via split-K
// z=4: grid (8,32,4)=1024 blocks = 4 blocks/CU (round-4's z=2 was grid-capped at 2/CU,
// OccupancyPercent 17.9 — the latency-bound regime). Single-buffer drain-0: co-resident
// block overlap (m114) beats explicit dbuf at lower occupancy (round-2 evidence).
__global__ __launch_bounds__(256) void k_gemm2_mfma(const __hip_bfloat16* __restrict__ softT,
                                                    const __hip_bfloat16* __restrict__ colsT,
                                                    float* __restrict__ patchP) {
    __shared__ __hip_bfloat16 As[128 * 64], Bs[128 * 64];
    int t = threadIdx.x, lane = t & 63, w = t >> 6;
    int wm = w & 1, wn = w >> 1;
    int flat = blockIdx.x + (blockIdx.y << 3) + (blockIdx.z << 8);  // grid (8,32,4) = 1024
    int swz = (flat & 7) * 128 + (flat >> 3);  // XCD k -> contiguous 128-block chunk
    int zp = swz >> 8;                         // 0..3
    int rem = swz & 255;
    int yp = rem >> 3, xp = rem & 7;
    int M0 = yp * 128, N0 = xp * 128;
    int kbase = zp * 1024;
    f32x4 acc[4][4] = {};
    for (int k0 = kbase; k0 < kbase + 1024; k0 += 64) {
#pragma unroll
        for (int rp = 0; rp < 4; ++rp) {
            int chunk = rp * 256 + t;
            int row = chunk >> 3;
            int kc = (chunk & 7) ^ (row & 7);
            async_copy16(softT + ((size_t)(M0 + row) << 12) + k0 + kc * 8, &As[chunk * 8]);
        }
#pragma unroll
        for (int rp = 0; rp < 4; ++rp) {
            int chunk = rp * 256 + t;
            int row = chunk >> 3;
            int kc = (chunk & 7) ^ (row & 7);
            async_copy16(colsT + ((size_t)(N0 + row) << 12) + k0 + kc * 8, &Bs[chunk * 8]);
        }
        __syncthreads();
        int qc = lane >> 4, mr = lane & 15;
#pragma unroll
        for (int kk = 0; kk < 2; ++kk) {
            int c = kk * 4 + qc;
            bf16x8 af[4], bfr[4];
#pragma unroll
            for (int i = 0; i < 4; ++i) {
                int rowa = wm * 64 + i * 16 + mr;
                af[i] = *(const bf16x8*)&As[rowa * 64 + (c ^ (rowa & 7)) * 8];
                int rowb = wn * 64 + i * 16 + mr;
                bfr[i] = *(const bf16x8*)&Bs[rowb * 64 + (c ^ (rowb & 7)) * 8];
            }
#pragma unroll
            for (int mt = 0; mt < 4; ++mt)
#pragma unroll
                for (int nt = 0; nt < 4; ++nt)
                    acc[mt][nt] = __builtin_amdgcn_mfma_f32_16x16x32_bf16(af[mt], bfr[nt], acc[mt][nt], 0, 0, 0);
        }
        __syncthreads();
    }
    float* P = patchP + ((size_t)zp << 22);
    int col = lane & 15, rq = (lane >> 4) * 4;
#pragma unroll
    for (int mt = 0; mt < 4; ++mt)
#pragma unroll
        for (int r = 0; r < 4; ++r) {
            int m = M0 + wm * 64 + mt * 16 + rq + r;
#pragma unroll
            for (int nt = 0; nt < 4; ++nt) {
                int n = N0 + wn * 64 + nt * 16 + col;
                P[(size_t)m * 1024 + n] = acc[mt][nt][r];
            }
        }
}

// ---------------- K7: overlap-add gather over all 4 K-partials, single batch --------------
__global__ void k_col2im(const float* __restrict__ patchP, float* __restrict__ outb) {
    int idx = blockIdx.x * 256 + threadIdx.x;  // C*H*W
    if (idx >= C_ * H_ * W_) return;
    int x = idx & 127, y = (idx >> 7) & 127, c = idx >> 14;
    const float* P0 = patchP;
    const float* P1 = patchP + (1u << 22);
    const float* P2 = patchP + (2u << 22);
    const float* P3 = patchP + (3u << 22);
    float acc = 0.f;
    int ki0 = (y + 1) & 1, kj0 = (x + 1) & 1;
#pragma unroll
    for (int ki = ki0; ki < 4; ki += 2) {
        int i = (y + 1 - ki) >> 1;
        if (i < 0 || i >= HS) continue;
#pragma unroll
        for (int kj = kj0; kj < 4; kj += 2) {
            int j = (x + 1 - kj) >> 1;
            if (j < 0 || j >= WS) continue;
            size_t off = ((size_t)(i * 64 + j) << 10) + c * 16 + ki * 4 + kj;
            acc += (P0[off] + P1[off]) + (P2[off] + P3[off]);
        }
    }
    outb[idx] = acc;
}

extern "C" void kernel_launch(void* const* d_in, const int* in_sizes, int n_in,
                              void* d_out, int out_size, void* d_ws, size_t ws_size,
                              hipStream_t stream) {
    (void)in_sizes; (void)n_in; (void)out_size; (void)ws_size;
    const float* fg = (const float*)d_in[0];
    const float* bg = (const float*)d_in[1];
    const float* mask = (const float*)d_in[2];
    float* out = (float*)d_out;

    // ---- workspace (float offsets), ~190 MiB envelope ----
    float* ws = (float*)d_ws;
    float* scores = ws;                                          // strip-only scores
    float* patchP = ws;                                          // alias: 4 x 4,194,304 f
    float* Y = ws + 16777216;                                    // 16,777,216 f
    _Float16* bgcol = (_Float16*)(ws + 33554432);                // 2,359,296 f16
    _Float16* fgcol = (_Float16*)(ws + 34734080);
    __hip_bfloat16* softT = (__hip_bfloat16*)(ws + 38273024);    // 16,777,216 bf16
    __hip_bfloat16* colsT = (__hip_bfloat16*)(ws + 46661632);    // 4,194,304 bf16
    float* pml = ws + 48758784;        // 262,144
    float* pz = ws + 49020928;         // 262,144
    float* denom_inv = ws + 49283072;  // 8,192 (B*L)
    float* maskedf = ws + 49291264;    // 8,192
    float* ssq = ws + 49299456;        // 8,192

    k_sumsq<<<(B_ * HS * WS) / 256, 256, 0, stream>>>(bg, ssq);
    k_patch_stats<<<(B_ * L_) / 256, 256, 0, stream>>>(mask, ssq, denom_inv, maskedf);

    for (int b = 0; b < B_; ++b) {
        const float* bgb = bg + (size_t)b * C_ * H_ * W_;
        const float* fgb = fg + (size_t)b * C_ * H_ * W_;

        k_prep<<<(2 * L_ * K1_ + NCOL * L_) / 256, 256, 0, stream>>>(bgb, fgb, bgcol, fgcol, colsT);

        dim3 g1(32, 32);
        k_gemm1_mfma<<<g1, 256, 0, stream>>>(bgcol, fgcol, denom_inv + b * L_, scores, Y);
        k_pass1_edge<<<2048, 256, 0, stream>>>(scores, Y);

        k_soft3<<<4096, 256, 0, stream>>>(Y, maskedf + b * L_, softT, pml, pz);
        k_zr<<<4096, 256, 0, stream>>>(pml, pz, softT);

        dim3 g5(8, 32, 4);
        k_gemm2_mfma<<<g5, 256, 0, stream>>>(softT, colsT, patchP);
        k_col2im<<<(C_ * H_ * W_) / 256, 256, 0, stream>>>(patchP, out + (size_t)b * C_ * H_ * W_);
    }
}

// Round 6
// 428.614 us; speedup vs baseline: 1.1640x; 1.1640x over previous
//
#include <hip/hip_runtime.h>
#include <hip/hip_bf16.h>

#define B_ 2
#define C_ 64
#define H_ 128
#define W_ 128
#define HS 64
#define WS 64
#define L_ 4096
#define S_ 4096
#define K1_ 576    // C*3*3
#define NCOL 1024  // C*4*4
#define SCALE_ 10.0f

typedef __attribute__((ext_vector_type(8))) short bf16x8;
typedef __attribute__((ext_vector_type(8))) _Float16 f16x8;
typedef __attribute__((ext_vector_type(4))) float f32x4;

// async global->LDS, 16B per lane (wave-uniform LDS base + lane*16).
__device__ __forceinline__ void async_copy16(const void* gsrc, void* ldst) {
    __builtin_amdgcn_global_load_lds(
        (__attribute__((address_space(1))) const void*)gsrc,
        (__attribute__((address_space(3))) void*)ldst, 16, 0, 0);
}

// transposed flat index within a 64x64 grid
__device__ __forceinline__ int TT(int x) { return ((x & 63) << 6) | (x >> 6); }

// generic 3-tap (d2) gather over Y with exact TT boundary semantics
__device__ __forceinline__ float diag3Y(const float* __restrict__ Y, int l, int s) {
    int tl = TT(l), ts = TT(s);
    float acc = 0.f;
#pragma unroll
    for (int d2 = -1; d2 <= 1; ++d2) {
        int p = tl + d2, q = ts + d2;
        if ((unsigned)p < 4096u && (unsigned)q < 4096u)
            acc += Y[((size_t)TT(p) << 12) + TT(q)];
    }
    return acc;
}

// ---------------- K0a: per-pixel channel sum-of-squares of downsampled bg ----------------
__global__ void k_sumsq(const float* __restrict__ bg, float* __restrict__ ssq) {
    int idx = blockIdx.x * 256 + threadIdx.x;  // B*64*64
    if (idx >= B_ * HS * WS) return;
    int pix = idx & 4095, b = idx >> 12;
    int i = pix >> 6, j = pix & 63;
    float ss = 0.f;
    for (int c = 0; c < C_; ++c) {
        float v = bg[((b * C_ + c) * H_ + 2 * i) * W_ + 2 * j];
        ss += v * v;
    }
    ssq[idx] = ss;
}

// ---------------- K0b: per-patch mask flag + 1/denom (3x3 box) ----------------
__global__ void k_patch_stats(const float* __restrict__ mask, const float* __restrict__ ssq,
                              float* __restrict__ denom_inv, float* __restrict__ maskedf) {
    int idx = blockIdx.x * 256 + threadIdx.x;  // B*L
    if (idx >= B_ * L_) return;
    int b = idx >> 12, l = idx & 4095, lh = l >> 6, lw = l & 63;
    float msum = 0.f, ss = 0.f;
    for (int di = -1; di <= 1; ++di)
        for (int dj = -1; dj <= 1; ++dj) {
            int i = lh + di, j = lw + dj;
            if (i >= 0 && i < HS && j >= 0 && j < WS) {
                msum += mask[(b * H_ + 2 * i) * W_ + 2 * j];
                ss += ssq[(b << 12) + (i << 6) + j];
            }
        }
    maskedf[idx] = (msum == 0.0f) ? 1.0f : 0.0f;
    denom_inv[idx] = 1.0f / fmaxf(sqrtf(ss), 0.001f);
}

// ---------------- K0c: fused prep: im2col (bg,fg -> fp16) + colsT (bf16), one launch ------
__global__ void k_prep(const float* __restrict__ bgb, const float* __restrict__ fgb,
                       _Float16* __restrict__ bcol, _Float16* __restrict__ fcol,
                       __hip_bfloat16* __restrict__ colsT) {
    int idx = blockIdx.x * 256 + threadIdx.x;
    if (idx < 2 * L_ * K1_) {  // im2col part (block-uniform split)
        int which = idx >= L_ * K1_;
        int id = which ? idx - L_ * K1_ : idx;
        const float* src = which ? fgb : bgb;
        _Float16* dst = which ? fcol : bcol;
        int k = id % K1_;
        int l = id / K1_;
        int c = k / 9, r = k - 9 * c;
        int r3 = r / 3;
        int di = r3 - 1, dj = r - 3 * r3 - 1;
        int i = (l >> 6) + di, j = (l & 63) + dj;
        float v = 0.f;
        if (i >= 0 && i < HS && j >= 0 && j < WS) v = src[(c * H_ + 2 * i) * W_ + 2 * j];
        dst[id] = (_Float16)v;
    } else {  // colsT part
        int id = idx - 2 * L_ * K1_;  // NCOL*L, l fastest
        int l = id & 4095, n = id >> 12;
        int kj = n & 3, ki = (n >> 2) & 3, c = n >> 4;
        int y = 2 * (l >> 6) + ki - 1, x = 2 * (l & 63) + kj - 1;
        float v = 0.f;
        if (y >= 0 && y < H_ && x >= 0 && x < W_) v = bgb[(c * H_ + y) * W_ + x];
        colsT[id] = __float2bfloat16(v);
    }
}

// ---------------- K1: scores GEMM (fp16, BK=64, XOR-8 swizzle, 2-deep pipelined) ----------
// Round-2 config (best measured: 46.5us).
__global__ __launch_bounds__(256) void k_gemm1_mfma(const _Float16* __restrict__ A,
                                                    const _Float16* __restrict__ Bm,
                                                    const float* __restrict__ dinv,
                                                    float* __restrict__ scores,
                                                    float* __restrict__ Y) {
    __shared__ __align__(16) char shraw[128 * 129 * 4];  // 66048B: 2x32KB staging / epi tile
    int t = threadIdx.x, lane = t & 63, w = t >> 6;
    int wm = w & 1, wn = w >> 1;
    int M0 = blockIdx.y * 128, N0 = blockIdx.x * 128;
    f32x4 acc[4][4] = {};

    auto stage = [&](int k0, int offh) {
        _Float16* Asb = (_Float16*)shraw + offh;
        _Float16* Bsb = Asb + 8192;
#pragma unroll
        for (int rp = 0; rp < 4; ++rp) {
            int chunk = rp * 256 + t;  // 1024 chunks of 16B
            int row = chunk >> 3;
            int kc = (chunk & 7) ^ (row & 7);  // permuted global chunk -> swizzled LDS store
            async_copy16(A + (size_t)(M0 + row) * K1_ + k0 + kc * 8, &Asb[chunk * 8]);
        }
#pragma unroll
        for (int rp = 0; rp < 4; ++rp) {
            int chunk = rp * 256 + t;
            int row = chunk >> 3;
            int kc = (chunk & 7) ^ (row & 7);
            async_copy16(Bm + (size_t)(N0 + row) * K1_ + k0 + kc * 8, &Bsb[chunk * 8]);
        }
    };

    stage(0, 0);
    int buf = 0;
    for (int k0 = 0; k0 < K1_; k0 += 64) {
        if (k0 + 64 < K1_) {
            stage(k0 + 64, (buf ^ 1) * 16384);
            asm volatile("s_waitcnt vmcnt(8)" ::: "memory");  // current tile landed
        } else {
            asm volatile("s_waitcnt vmcnt(0)" ::: "memory");
        }
        __builtin_amdgcn_s_barrier();
        _Float16* As = (_Float16*)shraw + buf * 16384;
        _Float16* Bs = As + 8192;
        int qc = lane >> 4, mr = lane & 15;
#pragma unroll
        for (int kk = 0; kk < 2; ++kk) {
            int c = kk * 4 + qc;
            f16x8 af[4], bfr[4];
#pragma unroll
            for (int i = 0; i < 4; ++i) {
                int ra = wm * 64 + i * 16 + mr;
                int rb = wn * 64 + i * 16 + mr;
                af[i] = *(const f16x8*)&As[ra * 64 + (c ^ (ra & 7)) * 8];
                bfr[i] = *(const f16x8*)&Bs[rb * 64 + (c ^ (rb & 7)) * 8];
            }
#pragma unroll
            for (int mt = 0; mt < 4; ++mt)
#pragma unroll
                for (int nt = 0; nt < 4; ++nt)
                    acc[mt][nt] = __builtin_amdgcn_mfma_f32_16x16x32_f16(af[mt], bfr[nt], acc[mt][nt], 0, 0, 0);
        }
        __builtin_amdgcn_s_barrier();  // readers done before next iter overwrites buf^1
        buf ^= 1;
    }
    int col = lane & 15, rq = (lane >> 4) * 4;
    // strip writes: raw scores on rows/cols {0,1,126,127} of this tile
#pragma unroll
    for (int mt = 0; mt < 4; ++mt)
#pragma unroll
        for (int r = 0; r < 4; ++r) {
            int ml = wm * 64 + mt * 16 + rq + r;
            bool rstrip = (ml <= 1) || (ml >= 126);
            float dv = dinv[M0 + ml];
#pragma unroll
            for (int nt = 0; nt < 4; ++nt) {
                int nl = wn * 64 + nt * 16 + col;
                bool cstrip = (nl <= 1) || (nl >= 126);
                if (rstrip || cstrip)
                    scores[((size_t)(M0 + ml) << 12) + N0 + nl] = acc[mt][nt][r] * dv;
            }
        }
    // Y interior via single full-tile LDS pass (128x129 f32)
    float* sm = (float*)shraw;
#pragma unroll
    for (int mt = 0; mt < 4; ++mt)
#pragma unroll
        for (int r = 0; r < 4; ++r) {
            int ml = wm * 64 + mt * 16 + rq + r;
            float dv = dinv[M0 + ml];
#pragma unroll
            for (int nt = 0; nt < 4; ++nt) {
                int nl = wn * 64 + nt * 16 + col;
                sm[ml * 129 + nl] = acc[mt][nt][r] * dv;
            }
        }
    __syncthreads();
    for (int e = t; e < 126 * 128; e += 256) {
        int rr = 1 + (e >> 7);
        int cc = e & 127;
        if (cc < 1 || cc > 126) continue;
        float y = sm[(rr - 1) * 129 + cc - 1] + sm[rr * 129 + cc] + sm[(rr + 1) * 129 + cc + 1];
        Y[((size_t)(M0 + rr) << 12) + N0 + cc] = y;
    }
}

// ---------------- K2a: Y boundary rows/cols from score strips (exact flat bounds) ---------
__global__ void k_pass1_edge(const float* __restrict__ scores, float* __restrict__ Y) {
    int idx = blockIdx.x * 256 + threadIdx.x;  // 2*64*4096
    int a, c;
    if (idx < 262144) {
        int ri = idx >> 12;  // 0..63
        a = (ri >> 1) * 128 + ((ri & 1) ? 127 : 0);
        c = idx & 4095;
    } else {
        int j = idx - 262144;
        int ci = j >> 12;
        c = (ci >> 1) * 128 + ((ci & 1) ? 127 : 0);
        a = j & 4095;
    }
    float acc = 0.f;
#pragma unroll
    for (int d = -1; d <= 1; ++d) {
        int aa = a + d, cc = c + d;
        if ((unsigned)aa < 4096u && (unsigned)cc < 4096u)
            acc += scores[((size_t)aa << 12) + cc];
    }
    Y[((size_t)a << 12) + c] = acc;
}

// ---------------- K2b: pass2 — 3-tap (rows +-64) + local-max exp + transpose -> softT -----
// Diagonal-major block walk + XCD-chunked swizzle (see round-0 notes); interior path
// register-prefetches all 12 float4 taps; pml/pz stored [s][lblock]; softT bf16x8 stores.
__global__ __launch_bounds__(256) void k_soft3(const float* __restrict__ Y,
                                               const float* __restrict__ maskedf,
                                               __hip_bfloat16* __restrict__ softT,
                                               float* __restrict__ pml, float* __restrict__ pz) {
    __shared__ float tile[64][65];
    __shared__ float red[16][64];
    __shared__ float mloc[64];
    int t = threadIdx.x;
    int sx4 = t & 15, lg = t >> 4;
    int bid = blockIdx.x;
    int swz = (bid & 7) * 512 + (bid >> 3);
    int dg = swz >> 6, pos = swz & 63;
    int by = pos, bx = (pos + dg) & 63;
    int s0 = bx * 64, l0 = by * 64;
    bool interior = (bx >= 1) && (bx <= 62) && (by >= 1) && (by <= 62);
    float p0 = -3.0e38f, p1 = -3.0e38f, p2 = -3.0e38f, p3 = -3.0e38f;
    if (interior) {
        float4 v[12];
        float mk[4];
#pragma unroll
        for (int j = 0; j < 4; ++j) {
            int lloc = lg + 16 * j;
#pragma unroll
            for (int d2 = 0; d2 < 3; ++d2) {
                const float* p = Y + ((size_t)(64 * (by + d2 - 1) + lloc) << 12) + 64 * (bx + d2 - 1) + 4 * sx4;
                v[j * 3 + d2] = *(const float4*)p;
            }
        }
#pragma unroll
        for (int j = 0; j < 4; ++j) mk[j] = maskedf[l0 + lg + 16 * j];
#pragma unroll
        for (int j = 0; j < 4; ++j) {
            int lloc = lg + 16 * j;
            float a0 = v[j * 3].x + v[j * 3 + 1].x + v[j * 3 + 2].x;
            float a1 = v[j * 3].y + v[j * 3 + 1].y + v[j * 3 + 2].y;
            float a2 = v[j * 3].z + v[j * 3 + 1].z + v[j * 3 + 2].z;
            float a3 = v[j * 3].w + v[j * 3 + 1].w + v[j * 3 + 2].w;
            if (mk[j] != 0.f) { a0 = -1000.f; a1 = -1000.f; a2 = -1000.f; a3 = -1000.f; }
            tile[lloc][4 * sx4 + 0] = a0;
            tile[lloc][4 * sx4 + 1] = a1;
            tile[lloc][4 * sx4 + 2] = a2;
            tile[lloc][4 * sx4 + 3] = a3;
            p0 = fmaxf(p0, a0); p1 = fmaxf(p1, a1); p2 = fmaxf(p2, a2); p3 = fmaxf(p3, a3);
        }
    } else {
#pragma unroll
        for (int j = 0; j < 4; ++j) {
            int lloc = lg + 16 * j;
            int l = l0 + lloc;
            bool mk = (maskedf[l] != 0.f);
            float a0 = mk ? -1000.f : diag3Y(Y, l, s0 + 4 * sx4 + 0);
            float a1 = mk ? -1000.f : diag3Y(Y, l, s0 + 4 * sx4 + 1);
            float a2 = mk ? -1000.f : diag3Y(Y, l, s0 + 4 * sx4 + 2);
            float a3 = mk ? -1000.f : diag3Y(Y, l, s0 + 4 * sx4 + 3);
            tile[lloc][4 * sx4 + 0] = a0;
            tile[lloc][4 * sx4 + 1] = a1;
            tile[lloc][4 * sx4 + 2] = a2;
            tile[lloc][4 * sx4 + 3] = a3;
            p0 = fmaxf(p0, a0); p1 = fmaxf(p1, a1); p2 = fmaxf(p2, a2); p3 = fmaxf(p3, a3);
        }
    }
    red[lg][4 * sx4 + 0] = p0;
    red[lg][4 * sx4 + 1] = p1;
    red[lg][4 * sx4 + 2] = p2;
    red[lg][4 * sx4 + 3] = p3;
    __syncthreads();
    if (t < 64) {
        float m = -3.0e38f;
#pragma unroll
        for (int g = 0; g < 16; ++g) m = fmaxf(m, red[g][t]);
        mloc[t] = m;
        pml[(size_t)(s0 + t) * 64 + by] = m;
    }
    __syncthreads();
    float m0 = mloc[4 * sx4 + 0], m1 = mloc[4 * sx4 + 1], m2 = mloc[4 * sx4 + 2], m3 = mloc[4 * sx4 + 3];
    float z0 = 0.f, z1 = 0.f, z2 = 0.f, z3 = 0.f;
#pragma unroll
    for (int j = 0; j < 4; ++j) {
        int lloc = lg + 16 * j;
        float e0 = __expf(SCALE_ * (tile[lloc][4 * sx4 + 0] - m0));
        float e1 = __expf(SCALE_ * (tile[lloc][4 * sx4 + 1] - m1));
        float e2 = __expf(SCALE_ * (tile[lloc][4 * sx4 + 2] - m2));
        float e3 = __expf(SCALE_ * (tile[lloc][4 * sx4 + 3] - m3));
        tile[lloc][4 * sx4 + 0] = e0;
        tile[lloc][4 * sx4 + 1] = e1;
        tile[lloc][4 * sx4 + 2] = e2;
        tile[lloc][4 * sx4 + 3] = e3;
        z0 += e0; z1 += e1; z2 += e2; z3 += e3;
    }
    red[lg][4 * sx4 + 0] = z0;
    red[lg][4 * sx4 + 1] = z1;
    red[lg][4 * sx4 + 2] = z2;
    red[lg][4 * sx4 + 3] = z3;
    __syncthreads();
    if (t < 64) {
        float zz = 0.f;
#pragma unroll
        for (int g = 0; g < 16; ++g) zz += red[g][t];
        pz[(size_t)(s0 + t) * 64 + by] = zz;
    }
#pragma unroll
    for (int pp = 0; pp < 2; ++pp) {
        int chunk = pp * 256 + t;
        int sloc = chunk >> 3, lb = (chunk & 7) * 8;
        bf16x8 o;
#pragma unroll
        for (int k = 0; k < 8; ++k) {
            __hip_bfloat16 r = __float2bfloat16(tile[lb + k][sloc]);
            o[k] = *reinterpret_cast<short*>(&r);
        }
        *(bf16x8*)(softT + ((size_t)(s0 + sloc) << 12) + l0 + lb) = o;
    }
}

// ---------------- K3: fused zfix+rescale: block per s-row --------------------------------
__global__ __launch_bounds__(256) void k_zr(const float* __restrict__ pml,
                                            const float* __restrict__ pz,
                                            __hip_bfloat16* __restrict__ softT) {
    __shared__ float facs[64];
    int t = threadIdx.x;
    int s = blockIdx.x;
    if (t < 64) {
        float pmv = pml[(size_t)s * 64 + t];
        float m = pmv;
#pragma unroll
        for (int off = 1; off < 64; off <<= 1) m = fmaxf(m, __shfl_xor(m, off));
        float fc = __expf(SCALE_ * (pmv - m));
        float g = pz[(size_t)s * 64 + t] * fc;
#pragma unroll
        for (int off = 1; off < 64; off <<= 1) g += __shfl_xor(g, off);
        facs[t] = fc * (1.0f / g);
    }
    __syncthreads();
    size_t rowbase = (size_t)s << 12;
#pragma unroll
    for (int p = 0; p < 2; ++p) {
        int chunk = t + p * 256;
        float f = facs[chunk >> 3];
        bf16x8 v = *(const bf16x8*)(softT + rowbase + chunk * 8);
        bf16x8 o;
#pragma unroll
        for (int k = 0; k < 8; ++k) {
            unsigned short us = (unsigned short)v[k];
            float x = __uint_as_float((unsigned)us << 16) * f;
            __hip_bfloat16 r = __float2bfloat16(x);
            o[k] = *reinterpret_cast<short*>(&r);
        }
        *(bf16x8*)(softT + rowbase + chunk * 8) = o;
    }
}

// ---------------- K6: deconv GEMM, split-K z=2, BM=128 BN=128 BK=64, 2-deep pipelined -----
// Round-6: round-4 structure (48.6us measured) + gemm1's counted-vmcnt dbuf pipeline.
// At BN=128 z=2 the grid (512 blocks) caps occupancy at 2 blocks/CU regardless of LDS,
// so the 2x32KB double-buffer is FREE (2x64KB = 128KB < 160KB/CU) — unlike round-2's
// BN=64 case where dbuf cost real TLP. stage(next) -> vmcnt(8) -> barrier -> MFMA.
__global__ __launch_bounds__(256) void k_gemm2_mfma(const __hip_bfloat16* __restrict__ softT,
                                                    const __hip_bfloat16* __restrict__ colsT,
                                                    float* __restrict__ patchP) {
    __shared__ __hip_bfloat16 AsB[2][16384];  // per buf: A 128x64 (8192) + B 128x64 (8192)
    int t = threadIdx.x, lane = t & 63, w = t >> 6;
    int wm = w & 1, wn = w >> 1;
    int flat = blockIdx.x + (blockIdx.y << 3) + (blockIdx.z << 8);  // grid (8,32,2) = 512
    int swz = (flat & 7) * 64 + (flat >> 3);  // XCD k -> contiguous 64-block chunk
    int zp = swz >> 8;
    int rem = swz & 255;
    int yp = rem >> 3, xp = rem & 7;
    int M0 = yp * 128, N0 = xp * 128;
    int kbase = zp * 2048;
    f32x4 acc[4][4] = {};

    auto stage = [&](int k0, int bsel) {
        __hip_bfloat16* Asb = AsB[bsel];
        __hip_bfloat16* Bsb = Asb + 8192;
#pragma unroll
        for (int rp = 0; rp < 4; ++rp) {
            int chunk = rp * 256 + t;
            int row = chunk >> 3;
            int kc = (chunk & 7) ^ (row & 7);
            async_copy16(softT + ((size_t)(M0 + row) << 12) + k0 + kc * 8, &Asb[chunk * 8]);
        }
#pragma unroll
        for (int rp = 0; rp < 4; ++rp) {
            int chunk = rp * 256 + t;
            int row = chunk >> 3;
            int kc = (chunk & 7) ^ (row & 7);
            async_copy16(colsT + ((size_t)(N0 + row) << 12) + k0 + kc * 8, &Bsb[chunk * 8]);
        }
    };

    stage(kbase, 0);
    int buf = 0;
    for (int k0 = kbase; k0 < kbase + 2048; k0 += 64) {
        if (k0 + 64 < kbase + 2048) {
            stage(k0 + 64, buf ^ 1);
            asm volatile("s_waitcnt vmcnt(8)" ::: "memory");  // current tile's 8 landed
        } else {
            asm volatile("s_waitcnt vmcnt(0)" ::: "memory");
        }
        __builtin_amdgcn_s_barrier();
        __hip_bfloat16* As = AsB[buf];
        __hip_bfloat16* Bs = As + 8192;
        int qc = lane >> 4, mr = lane & 15;
#pragma unroll
        for (int kk = 0; kk < 2; ++kk) {
            int c = kk * 4 + qc;
            bf16x8 af[4], bfr[4];
#pragma unroll
            for (int i = 0; i < 4; ++i) {
                int rowa = wm * 64 + i * 16 + mr;
                af[i] = *(const bf16x8*)&As[rowa * 64 + (c ^ (rowa & 7)) * 8];
                int rowb = wn * 64 + i * 16 + mr;
                bfr[i] = *(const bf16x8*)&Bs[rowb * 64 + (c ^ (rowb & 7)) * 8];
            }
#pragma unroll
            for (int mt = 0; mt < 4; ++mt)
#pragma unroll
                for (int nt = 0; nt < 4; ++nt)
                    acc[mt][nt] = __builtin_amdgcn_mfma_f32_16x16x32_bf16(af[mt], bfr[nt], acc[mt][nt], 0, 0, 0);
        }
        __builtin_amdgcn_s_barrier();  // readers done before next iter overwrites buf^1
        buf ^= 1;
    }
    float* P = patchP + ((size_t)zp << 22);
    int col = lane & 15, rq = (lane >> 4) * 4;
#pragma unroll
    for (int mt = 0; mt < 4; ++mt)
#pragma unroll
        for (int r = 0; r < 4; ++r) {
            int m = M0 + wm * 64 + mt * 16 + rq + r;
#pragma unroll
            for (int nt = 0; nt < 4; ++nt) {
                int n = N0 + wn * 64 + nt * 16 + col;
                P[(size_t)m * 1024 + n] = acc[mt][nt][r];
            }
        }
}

// ---------------- K7: overlap-add gather over both K-partials, single batch ---------------
__global__ void k_col2im(const float* __restrict__ patchP, float* __restrict__ outb) {
    int idx = blockIdx.x * 256 + threadIdx.x;  // C*H*W
    if (idx >= C_ * H_ * W_) return;
    int x = idx & 127, y = (idx >> 7) & 127, c = idx >> 14;
    const float* P0 = patchP;
    const float* P1 = patchP + (1u << 22);
    float acc = 0.f;
    int ki0 = (y + 1) & 1, kj0 = (x + 1) & 1;
#pragma unroll
    for (int ki = ki0; ki < 4; ki += 2) {
        int i = (y + 1 - ki) >> 1;
        if (i < 0 || i >= HS) continue;
#pragma unroll
        for (int kj = kj0; kj < 4; kj += 2) {
            int j = (x + 1 - kj) >> 1;
            if (j < 0 || j >= WS) continue;
            size_t off = ((size_t)(i * 64 + j) << 10) + c * 16 + ki * 4 + kj;
            acc += P0[off] + P1[off];
        }
    }
    outb[idx] = acc;
}

extern "C" void kernel_launch(void* const* d_in, const int* in_sizes, int n_in,
                              void* d_out, int out_size, void* d_ws, size_t ws_size,
                              hipStream_t stream) {
    (void)in_sizes; (void)n_in; (void)out_size; (void)ws_size;
    const float* fg = (const float*)d_in[0];
    const float* bg = (const float*)d_in[1];
    const float* mask = (const float*)d_in[2];
    float* out = (float*)d_out;

    // ---- workspace (float offsets), ~190 MiB envelope ----
    float* ws = (float*)d_ws;
    float* scores = ws;                                          // strip-only scores
    float* patchP = ws;                                          // alias: 2 x 4,194,304 f
    float* Y = ws + 16777216;                                    // 16,777,216 f
    _Float16* bgcol = (_Float16*)(ws + 33554432);                // 2,359,296 f16
    _Float16* fgcol = (_Float16*)(ws + 34734080);
    __hip_bfloat16* softT = (__hip_bfloat16*)(ws + 38273024);    // 16,777,216 bf16
    __hip_bfloat16* colsT = (__hip_bfloat16*)(ws + 46661632);    // 4,194,304 bf16
    float* pml = ws + 48758784;        // 262,144
    float* pz = ws + 49020928;         // 262,144
    float* denom_inv = ws + 49283072;  // 8,192 (B*L)
    float* maskedf = ws + 49291264;    // 8,192
    float* ssq = ws + 49299456;        // 8,192

    k_sumsq<<<(B_ * HS * WS) / 256, 256, 0, stream>>>(bg, ssq);
    k_patch_stats<<<(B_ * L_) / 256, 256, 0, stream>>>(mask, ssq, denom_inv, maskedf);

    for (int b = 0; b < B_; ++b) {
        const float* bgb = bg + (size_t)b * C_ * H_ * W_;
        const float* fgb = fg + (size_t)b * C_ * H_ * W_;

        k_prep<<<(2 * L_ * K1_ + NCOL * L_) / 256, 256, 0, stream>>>(bgb, fgb, bgcol, fgcol, colsT);

        dim3 g1(32, 32);
        k_gemm1_mfma<<<g1, 256, 0, stream>>>(bgcol, fgcol, denom_inv + b * L_, scores, Y);
        k_pass1_edge<<<2048, 256, 0, stream>>>(scores, Y);

        k_soft3<<<4096, 256, 0, stream>>>(Y, maskedf + b * L_, softT, pml, pz);
        k_zr<<<4096, 256, 0, stream>>>(pml, pz, softT);

        dim3 g5(8, 32, 2);
        k_gemm2_mfma<<<g5, 256, 0, stream>>>(softT, colsT, patchP);
        k_col2im<<<(C_ * H_ * W_) / 256, 256, 0, stream>>>(patchP, out + (size_t)b * C_ * H_ * W_);
    }
}

// Round 7
// 399.936 us; speedup vs baseline: 1.2474x; 1.0717x over previous
//
#include <hip/hip_runtime.h>
#include <hip/hip_bf16.h>

#define B_ 2
#define C_ 64
#define H_ 128
#define W_ 128
#define HS 64
#define WS 64
#define L_ 4096
#define S_ 4096
#define K1_ 576    // C*3*3
#define NCOL 1024  // C*4*4
#define SCALE_ 10.0f

typedef __attribute__((ext_vector_type(8))) short bf16x8;
typedef __attribute__((ext_vector_type(8))) _Float16 f16x8;
typedef __attribute__((ext_vector_type(4))) float f32x4;

// async global->LDS, 16B per lane (wave-uniform LDS base + lane*16).
__device__ __forceinline__ void async_copy16(const void* gsrc, void* ldst) {
    __builtin_amdgcn_global_load_lds(
        (__attribute__((address_space(1))) const void*)gsrc,
        (__attribute__((address_space(3))) void*)ldst, 16, 0, 0);
}

// transposed flat index within a 64x64 grid
__device__ __forceinline__ int TT(int x) { return ((x & 63) << 6) | (x >> 6); }

// generic 3-tap (d2) gather over Y with exact TT boundary semantics
__device__ __forceinline__ float diag3Y(const float* __restrict__ Y, int l, int s) {
    int tl = TT(l), ts = TT(s);
    float acc = 0.f;
#pragma unroll
    for (int d2 = -1; d2 <= 1; ++d2) {
        int p = tl + d2, q = ts + d2;
        if ((unsigned)p < 4096u && (unsigned)q < 4096u)
            acc += Y[((size_t)TT(p) << 12) + TT(q)];
    }
    return acc;
}

// ---------------- K0a: per-pixel channel sum-of-squares of downsampled bg ----------------
__global__ void k_sumsq(const float* __restrict__ bg, float* __restrict__ ssq) {
    int idx = blockIdx.x * 256 + threadIdx.x;  // B*64*64
    if (idx >= B_ * HS * WS) return;
    int pix = idx & 4095, b = idx >> 12;
    int i = pix >> 6, j = pix & 63;
    float ss = 0.f;
    for (int c = 0; c < C_; ++c) {
        float v = bg[((b * C_ + c) * H_ + 2 * i) * W_ + 2 * j];
        ss += v * v;
    }
    ssq[idx] = ss;
}

// ---------------- K0b: per-patch mask flag + 1/denom (3x3 box) ----------------
__global__ void k_patch_stats(const float* __restrict__ mask, const float* __restrict__ ssq,
                              float* __restrict__ denom_inv, float* __restrict__ maskedf) {
    int idx = blockIdx.x * 256 + threadIdx.x;  // B*L
    if (idx >= B_ * L_) return;
    int b = idx >> 12, l = idx & 4095, lh = l >> 6, lw = l & 63;
    float msum = 0.f, ss = 0.f;
    for (int di = -1; di <= 1; ++di)
        for (int dj = -1; dj <= 1; ++dj) {
            int i = lh + di, j = lw + dj;
            if (i >= 0 && i < HS && j >= 0 && j < WS) {
                msum += mask[(b * H_ + 2 * i) * W_ + 2 * j];
                ss += ssq[(b << 12) + (i << 6) + j];
            }
        }
    maskedf[idx] = (msum == 0.0f) ? 1.0f : 0.0f;
    denom_inv[idx] = 1.0f / fmaxf(sqrtf(ss), 0.001f);
}

// ---------------- K0c: fused prep: im2col (bg,fg -> fp16) + colsT (bf16), one launch ------
__global__ void k_prep(const float* __restrict__ bgb, const float* __restrict__ fgb,
                       _Float16* __restrict__ bcol, _Float16* __restrict__ fcol,
                       __hip_bfloat16* __restrict__ colsT) {
    int idx = blockIdx.x * 256 + threadIdx.x;
    if (idx < 2 * L_ * K1_) {  // im2col part (block-uniform split)
        int which = idx >= L_ * K1_;
        int id = which ? idx - L_ * K1_ : idx;
        const float* src = which ? fgb : bgb;
        _Float16* dst = which ? fcol : bcol;
        int k = id % K1_;
        int l = id / K1_;
        int c = k / 9, r = k - 9 * c;
        int r3 = r / 3;
        int di = r3 - 1, dj = r - 3 * r3 - 1;
        int i = (l >> 6) + di, j = (l & 63) + dj;
        float v = 0.f;
        if (i >= 0 && i < HS && j >= 0 && j < WS) v = src[(c * H_ + 2 * i) * W_ + 2 * j];
        dst[id] = (_Float16)v;
    } else {  // colsT part
        int id = idx - 2 * L_ * K1_;  // NCOL*L, l fastest
        int l = id & 4095, n = id >> 12;
        int kj = n & 3, ki = (n >> 2) & 3, c = n >> 4;
        int y = 2 * (l >> 6) + ki - 1, x = 2 * (l & 63) + kj - 1;
        float v = 0.f;
        if (y >= 0 && y < H_ && x >= 0 && x < W_) v = bgb[(c * H_ + y) * W_ + x];
        colsT[id] = __float2bfloat16(v);
    }
}

// ---------------- K1: scores GEMM (fp16, BK=64, XOR-8 swizzle, 2-deep pipelined) ----------
// Round-2 config (best measured: 46.5us).
__global__ __launch_bounds__(256) void k_gemm1_mfma(const _Float16* __restrict__ A,
                                                    const _Float16* __restrict__ Bm,
                                                    const float* __restrict__ dinv,
                                                    float* __restrict__ scores,
                                                    float* __restrict__ Y) {
    __shared__ __align__(16) char shraw[128 * 129 * 4];  // 66048B: 2x32KB staging / epi tile
    int t = threadIdx.x, lane = t & 63, w = t >> 6;
    int wm = w & 1, wn = w >> 1;
    int M0 = blockIdx.y * 128, N0 = blockIdx.x * 128;
    f32x4 acc[4][4] = {};

    auto stage = [&](int k0, int offh) {
        _Float16* Asb = (_Float16*)shraw + offh;
        _Float16* Bsb = Asb + 8192;
#pragma unroll
        for (int rp = 0; rp < 4; ++rp) {
            int chunk = rp * 256 + t;  // 1024 chunks of 16B
            int row = chunk >> 3;
            int kc = (chunk & 7) ^ (row & 7);  // permuted global chunk -> swizzled LDS store
            async_copy16(A + (size_t)(M0 + row) * K1_ + k0 + kc * 8, &Asb[chunk * 8]);
        }
#pragma unroll
        for (int rp = 0; rp < 4; ++rp) {
            int chunk = rp * 256 + t;
            int row = chunk >> 3;
            int kc = (chunk & 7) ^ (row & 7);
            async_copy16(Bm + (size_t)(N0 + row) * K1_ + k0 + kc * 8, &Bsb[chunk * 8]);
        }
    };

    stage(0, 0);
    int buf = 0;
    for (int k0 = 0; k0 < K1_; k0 += 64) {
        if (k0 + 64 < K1_) {
            stage(k0 + 64, (buf ^ 1) * 16384);
            asm volatile("s_waitcnt vmcnt(8)" ::: "memory");  // current tile landed
        } else {
            asm volatile("s_waitcnt vmcnt(0)" ::: "memory");
        }
        __builtin_amdgcn_s_barrier();
        _Float16* As = (_Float16*)shraw + buf * 16384;
        _Float16* Bs = As + 8192;
        int qc = lane >> 4, mr = lane & 15;
#pragma unroll
        for (int kk = 0; kk < 2; ++kk) {
            int c = kk * 4 + qc;
            f16x8 af[4], bfr[4];
#pragma unroll
            for (int i = 0; i < 4; ++i) {
                int ra = wm * 64 + i * 16 + mr;
                int rb = wn * 64 + i * 16 + mr;
                af[i] = *(const f16x8*)&As[ra * 64 + (c ^ (ra & 7)) * 8];
                bfr[i] = *(const f16x8*)&Bs[rb * 64 + (c ^ (rb & 7)) * 8];
            }
#pragma unroll
            for (int mt = 0; mt < 4; ++mt)
#pragma unroll
                for (int nt = 0; nt < 4; ++nt)
                    acc[mt][nt] = __builtin_amdgcn_mfma_f32_16x16x32_f16(af[mt], bfr[nt], acc[mt][nt], 0, 0, 0);
        }
        __builtin_amdgcn_s_barrier();  // readers done before next iter overwrites buf^1
        buf ^= 1;
    }
    int col = lane & 15, rq = (lane >> 4) * 4;
    // strip writes: raw scores on rows/cols {0,1,126,127} of this tile
#pragma unroll
    for (int mt = 0; mt < 4; ++mt)
#pragma unroll
        for (int r = 0; r < 4; ++r) {
            int ml = wm * 64 + mt * 16 + rq + r;
            bool rstrip = (ml <= 1) || (ml >= 126);
            float dv = dinv[M0 + ml];
#pragma unroll
            for (int nt = 0; nt < 4; ++nt) {
                int nl = wn * 64 + nt * 16 + col;
                bool cstrip = (nl <= 1) || (nl >= 126);
                if (rstrip || cstrip)
                    scores[((size_t)(M0 + ml) << 12) + N0 + nl] = acc[mt][nt][r] * dv;
            }
        }
    // Y interior via single full-tile LDS pass (128x129 f32)
    float* sm = (float*)shraw;
#pragma unroll
    for (int mt = 0; mt < 4; ++mt)
#pragma unroll
        for (int r = 0; r < 4; ++r) {
            int ml = wm * 64 + mt * 16 + rq + r;
            float dv = dinv[M0 + ml];
#pragma unroll
            for (int nt = 0; nt < 4; ++nt) {
                int nl = wn * 64 + nt * 16 + col;
                sm[ml * 129 + nl] = acc[mt][nt][r] * dv;
            }
        }
    __syncthreads();
    for (int e = t; e < 126 * 128; e += 256) {
        int rr = 1 + (e >> 7);
        int cc = e & 127;
        if (cc < 1 || cc > 126) continue;
        float y = sm[(rr - 1) * 129 + cc - 1] + sm[rr * 129 + cc] + sm[(rr + 1) * 129 + cc + 1];
        Y[((size_t)(M0 + rr) << 12) + N0 + cc] = y;
    }
}

// ---------------- K2a: Y boundary rows/cols from score strips (exact flat bounds) ---------
__global__ void k_pass1_edge(const float* __restrict__ scores, float* __restrict__ Y) {
    int idx = blockIdx.x * 256 + threadIdx.x;  // 2*64*4096
    int a, c;
    if (idx < 262144) {
        int ri = idx >> 12;  // 0..63
        a = (ri >> 1) * 128 + ((ri & 1) ? 127 : 0);
        c = idx & 4095;
    } else {
        int j = idx - 262144;
        int ci = j >> 12;
        c = (ci >> 1) * 128 + ((ci & 1) ? 127 : 0);
        a = j & 4095;
    }
    float acc = 0.f;
#pragma unroll
    for (int d = -1; d <= 1; ++d) {
        int aa = a + d, cc = c + d;
        if ((unsigned)aa < 4096u && (unsigned)cc < 4096u)
            acc += scores[((size_t)aa << 12) + cc];
    }
    Y[((size_t)a << 12) + c] = acc;
}

// ---------------- K2b: pass2 — 3-tap (rows +-64) + local-max exp + transpose -> softT -----
// Diagonal-major block walk + XCD-chunked swizzle (see round-0 notes); interior path
// register-prefetches all 12 float4 taps; pml/pz stored [s][lblock]; softT bf16x8 stores.
__global__ __launch_bounds__(256) void k_soft3(const float* __restrict__ Y,
                                               const float* __restrict__ maskedf,
                                               __hip_bfloat16* __restrict__ softT,
                                               float* __restrict__ pml, float* __restrict__ pz) {
    __shared__ float tile[64][65];
    __shared__ float red[16][64];
    __shared__ float mloc[64];
    int t = threadIdx.x;
    int sx4 = t & 15, lg = t >> 4;
    int bid = blockIdx.x;
    int swz = (bid & 7) * 512 + (bid >> 3);
    int dg = swz >> 6, pos = swz & 63;
    int by = pos, bx = (pos + dg) & 63;
    int s0 = bx * 64, l0 = by * 64;
    bool interior = (bx >= 1) && (bx <= 62) && (by >= 1) && (by <= 62);
    float p0 = -3.0e38f, p1 = -3.0e38f, p2 = -3.0e38f, p3 = -3.0e38f;
    if (interior) {
        float4 v[12];
        float mk[4];
#pragma unroll
        for (int j = 0; j < 4; ++j) {
            int lloc = lg + 16 * j;
#pragma unroll
            for (int d2 = 0; d2 < 3; ++d2) {
                const float* p = Y + ((size_t)(64 * (by + d2 - 1) + lloc) << 12) + 64 * (bx + d2 - 1) + 4 * sx4;
                v[j * 3 + d2] = *(const float4*)p;
            }
        }
#pragma unroll
        for (int j = 0; j < 4; ++j) mk[j] = maskedf[l0 + lg + 16 * j];
#pragma unroll
        for (int j = 0; j < 4; ++j) {
            int lloc = lg + 16 * j;
            float a0 = v[j * 3].x + v[j * 3 + 1].x + v[j * 3 + 2].x;
            float a1 = v[j * 3].y + v[j * 3 + 1].y + v[j * 3 + 2].y;
            float a2 = v[j * 3].z + v[j * 3 + 1].z + v[j * 3 + 2].z;
            float a3 = v[j * 3].w + v[j * 3 + 1].w + v[j * 3 + 2].w;
            if (mk[j] != 0.f) { a0 = -1000.f; a1 = -1000.f; a2 = -1000.f; a3 = -1000.f; }
            tile[lloc][4 * sx4 + 0] = a0;
            tile[lloc][4 * sx4 + 1] = a1;
            tile[lloc][4 * sx4 + 2] = a2;
            tile[lloc][4 * sx4 + 3] = a3;
            p0 = fmaxf(p0, a0); p1 = fmaxf(p1, a1); p2 = fmaxf(p2, a2); p3 = fmaxf(p3, a3);
        }
    } else {
#pragma unroll
        for (int j = 0; j < 4; ++j) {
            int lloc = lg + 16 * j;
            int l = l0 + lloc;
            bool mk = (maskedf[l] != 0.f);
            float a0 = mk ? -1000.f : diag3Y(Y, l, s0 + 4 * sx4 + 0);
            float a1 = mk ? -1000.f : diag3Y(Y, l, s0 + 4 * sx4 + 1);
            float a2 = mk ? -1000.f : diag3Y(Y, l, s0 + 4 * sx4 + 2);
            float a3 = mk ? -1000.f : diag3Y(Y, l, s0 + 4 * sx4 + 3);
            tile[lloc][4 * sx4 + 0] = a0;
            tile[lloc][4 * sx4 + 1] = a1;
            tile[lloc][4 * sx4 + 2] = a2;
            tile[lloc][4 * sx4 + 3] = a3;
            p0 = fmaxf(p0, a0); p1 = fmaxf(p1, a1); p2 = fmaxf(p2, a2); p3 = fmaxf(p3, a3);
        }
    }
    red[lg][4 * sx4 + 0] = p0;
    red[lg][4 * sx4 + 1] = p1;
    red[lg][4 * sx4 + 2] = p2;
    red[lg][4 * sx4 + 3] = p3;
    __syncthreads();
    if (t < 64) {
        float m = -3.0e38f;
#pragma unroll
        for (int g = 0; g < 16; ++g) m = fmaxf(m, red[g][t]);
        mloc[t] = m;
        pml[(size_t)(s0 + t) * 64 + by] = m;
    }
    __syncthreads();
    float m0 = mloc[4 * sx4 + 0], m1 = mloc[4 * sx4 + 1], m2 = mloc[4 * sx4 + 2], m3 = mloc[4 * sx4 + 3];
    float z0 = 0.f, z1 = 0.f, z2 = 0.f, z3 = 0.f;
#pragma unroll
    for (int j = 0; j < 4; ++j) {
        int lloc = lg + 16 * j;
        float e0 = __expf(SCALE_ * (tile[lloc][4 * sx4 + 0] - m0));
        float e1 = __expf(SCALE_ * (tile[lloc][4 * sx4 + 1] - m1));
        float e2 = __expf(SCALE_ * (tile[lloc][4 * sx4 + 2] - m2));
        float e3 = __expf(SCALE_ * (tile[lloc][4 * sx4 + 3] - m3));
        tile[lloc][4 * sx4 + 0] = e0;
        tile[lloc][4 * sx4 + 1] = e1;
        tile[lloc][4 * sx4 + 2] = e2;
        tile[lloc][4 * sx4 + 3] = e3;
        z0 += e0; z1 += e1; z2 += e2; z3 += e3;
    }
    red[lg][4 * sx4 + 0] = z0;
    red[lg][4 * sx4 + 1] = z1;
    red[lg][4 * sx4 + 2] = z2;
    red[lg][4 * sx4 + 3] = z3;
    __syncthreads();
    if (t < 64) {
        float zz = 0.f;
#pragma unroll
        for (int g = 0; g < 16; ++g) zz += red[g][t];
        pz[(size_t)(s0 + t) * 64 + by] = zz;
    }
#pragma unroll
    for (int pp = 0; pp < 2; ++pp) {
        int chunk = pp * 256 + t;
        int sloc = chunk >> 3, lb = (chunk & 7) * 8;
        bf16x8 o;
#pragma unroll
        for (int k = 0; k < 8; ++k) {
            __hip_bfloat16 r = __float2bfloat16(tile[lb + k][sloc]);
            o[k] = *reinterpret_cast<short*>(&r);
        }
        *(bf16x8*)(softT + ((size_t)(s0 + sloc) << 12) + l0 + lb) = o;
    }
}

// ---------------- K3: fused zfix+rescale: block per s-row --------------------------------
__global__ __launch_bounds__(256) void k_zr(const float* __restrict__ pml,
                                            const float* __restrict__ pz,
                                            __hip_bfloat16* __restrict__ softT) {
    __shared__ float facs[64];
    int t = threadIdx.x;
    int s = blockIdx.x;
    if (t < 64) {
        float pmv = pml[(size_t)s * 64 + t];
        float m = pmv;
#pragma unroll
        for (int off = 1; off < 64; off <<= 1) m = fmaxf(m, __shfl_xor(m, off));
        float fc = __expf(SCALE_ * (pmv - m));
        float g = pz[(size_t)s * 64 + t] * fc;
#pragma unroll
        for (int off = 1; off < 64; off <<= 1) g += __shfl_xor(g, off);
        facs[t] = fc * (1.0f / g);
    }
    __syncthreads();
    size_t rowbase = (size_t)s << 12;
#pragma unroll
    for (int p = 0; p < 2; ++p) {
        int chunk = t + p * 256;
        float f = facs[chunk >> 3];
        bf16x8 v = *(const bf16x8*)(softT + rowbase + chunk * 8);
        bf16x8 o;
#pragma unroll
        for (int k = 0; k < 8; ++k) {
            unsigned short us = (unsigned short)v[k];
            float x = __uint_as_float((unsigned)us << 16) * f;
            __hip_bfloat16 r = __float2bfloat16(x);
            o[k] = *reinterpret_cast<short*>(&r);
        }
        *(bf16x8*)(softT + rowbase + chunk * 8) = o;
    }
}

// ---------------- K6: deconv GEMM, split-K z=2, BM=128 BN=128 BK=64, 2-deep pipelined -----
// Round-7: epilogue writes patchP n-major (P[n][m], float4 over the 4 consecutive m of
// acc's r-components) so col2im's gather becomes coalesced. K-loop unchanged (round-6).
__global__ __launch_bounds__(256) void k_gemm2_mfma(const __hip_bfloat16* __restrict__ softT,
                                                    const __hip_bfloat16* __restrict__ colsT,
                                                    float* __restrict__ patchP) {
    __shared__ __hip_bfloat16 AsB[2][16384];  // per buf: A 128x64 (8192) + B 128x64 (8192)
    int t = threadIdx.x, lane = t & 63, w = t >> 6;
    int wm = w & 1, wn = w >> 1;
    int flat = blockIdx.x + (blockIdx.y << 3) + (blockIdx.z << 8);  // grid (8,32,2) = 512
    int swz = (flat & 7) * 64 + (flat >> 3);  // XCD k -> contiguous 64-block chunk
    int zp = swz >> 8;
    int rem = swz & 255;
    int yp = rem >> 3, xp = rem & 7;
    int M0 = yp * 128, N0 = xp * 128;
    int kbase = zp * 2048;
    f32x4 acc[4][4] = {};

    auto stage = [&](int k0, int bsel) {
        __hip_bfloat16* Asb = AsB[bsel];
        __hip_bfloat16* Bsb = Asb + 8192;
#pragma unroll
        for (int rp = 0; rp < 4; ++rp) {
            int chunk = rp * 256 + t;
            int row = chunk >> 3;
            int kc = (chunk & 7) ^ (row & 7);
            async_copy16(softT + ((size_t)(M0 + row) << 12) + k0 + kc * 8, &Asb[chunk * 8]);
        }
#pragma unroll
        for (int rp = 0; rp < 4; ++rp) {
            int chunk = rp * 256 + t;
            int row = chunk >> 3;
            int kc = (chunk & 7) ^ (row & 7);
            async_copy16(colsT + ((size_t)(N0 + row) << 12) + k0 + kc * 8, &Bsb[chunk * 8]);
        }
    };

    stage(kbase, 0);
    int buf = 0;
    for (int k0 = kbase; k0 < kbase + 2048; k0 += 64) {
        if (k0 + 64 < kbase + 2048) {
            stage(k0 + 64, buf ^ 1);
            asm volatile("s_waitcnt vmcnt(8)" ::: "memory");  // current tile's 8 landed
        } else {
            asm volatile("s_waitcnt vmcnt(0)" ::: "memory");
        }
        __builtin_amdgcn_s_barrier();
        __hip_bfloat16* As = AsB[buf];
        __hip_bfloat16* Bs = As + 8192;
        int qc = lane >> 4, mr = lane & 15;
#pragma unroll
        for (int kk = 0; kk < 2; ++kk) {
            int c = kk * 4 + qc;
            bf16x8 af[4], bfr[4];
#pragma unroll
            for (int i = 0; i < 4; ++i) {
                int rowa = wm * 64 + i * 16 + mr;
                af[i] = *(const bf16x8*)&As[rowa * 64 + (c ^ (rowa & 7)) * 8];
                int rowb = wn * 64 + i * 16 + mr;
                bfr[i] = *(const bf16x8*)&Bs[rowb * 64 + (c ^ (rowb & 7)) * 8];
            }
#pragma unroll
            for (int mt = 0; mt < 4; ++mt)
#pragma unroll
                for (int nt = 0; nt < 4; ++nt)
                    acc[mt][nt] = __builtin_amdgcn_mfma_f32_16x16x32_bf16(af[mt], bfr[nt], acc[mt][nt], 0, 0, 0);
        }
        __builtin_amdgcn_s_barrier();  // readers done before next iter overwrites buf^1
        buf ^= 1;
    }
    // n-major epilogue: P[n*4096 + m], 16B-aligned float4 per (mt,nt) (r -> m0+0..3)
    float* P = patchP + ((size_t)zp << 22);
    int col = lane & 15, rq = (lane >> 4) * 4;
#pragma unroll
    for (int mt = 0; mt < 4; ++mt) {
        int m0 = M0 + wm * 64 + mt * 16 + rq;
#pragma unroll
        for (int nt = 0; nt < 4; ++nt) {
            int n = N0 + wn * 64 + nt * 16 + col;
            *(f32x4*)&P[(size_t)n * 4096 + m0] = acc[mt][nt];
        }
    }
}

// ---------------- K7: overlap-add gather over both K-partials, n-major patchP -------------
// off = n*4096 + l: for fixed (c,ki,kj), consecutive x -> consecutive j -> coalesced reads.
__global__ void k_col2im(const float* __restrict__ patchP, float* __restrict__ outb) {
    int idx = blockIdx.x * 256 + threadIdx.x;  // C*H*W
    if (idx >= C_ * H_ * W_) return;
    int x = idx & 127, y = (idx >> 7) & 127, c = idx >> 14;
    const float* P0 = patchP;
    const float* P1 = patchP + (1u << 22);
    float acc = 0.f;
    int ki0 = (y + 1) & 1, kj0 = (x + 1) & 1;
#pragma unroll
    for (int ki = ki0; ki < 4; ki += 2) {
        int i = (y + 1 - ki) >> 1;
        if (i < 0 || i >= HS) continue;
#pragma unroll
        for (int kj = kj0; kj < 4; kj += 2) {
            int j = (x + 1 - kj) >> 1;
            if (j < 0 || j >= WS) continue;
            size_t off = ((size_t)(c * 16 + ki * 4 + kj) << 12) + i * 64 + j;
            acc += P0[off] + P1[off];
        }
    }
    outb[idx] = acc;
}

extern "C" void kernel_launch(void* const* d_in, const int* in_sizes, int n_in,
                              void* d_out, int out_size, void* d_ws, size_t ws_size,
                              hipStream_t stream) {
    (void)in_sizes; (void)n_in; (void)out_size; (void)ws_size;
    const float* fg = (const float*)d_in[0];
    const float* bg = (const float*)d_in[1];
    const float* mask = (const float*)d_in[2];
    float* out = (float*)d_out;

    // ---- workspace (float offsets), ~190 MiB envelope ----
    float* ws = (float*)d_ws;
    float* scores = ws;                                          // strip-only scores
    float* patchP = ws;                                          // alias: 2 x 4,194,304 f
    float* Y = ws + 16777216;                                    // 16,777,216 f
    _Float16* bgcol = (_Float16*)(ws + 33554432);                // 2,359,296 f16
    _Float16* fgcol = (_Float16*)(ws + 34734080);
    __hip_bfloat16* softT = (__hip_bfloat16*)(ws + 38273024);    // 16,777,216 bf16
    __hip_bfloat16* colsT = (__hip_bfloat16*)(ws + 46661632);    // 4,194,304 bf16
    float* pml = ws + 48758784;        // 262,144
    float* pz = ws + 49020928;         // 262,144
    float* denom_inv = ws + 49283072;  // 8,192 (B*L)
    float* maskedf = ws + 49291264;    // 8,192
    float* ssq = ws + 49299456;        // 8,192

    k_sumsq<<<(B_ * HS * WS) / 256, 256, 0, stream>>>(bg, ssq);
    k_patch_stats<<<(B_ * L_) / 256, 256, 0, stream>>>(mask, ssq, denom_inv, maskedf);

    for (int b = 0; b < B_; ++b) {
        const float* bgb = bg + (size_t)b * C_ * H_ * W_;
        const float* fgb = fg + (size_t)b * C_ * H_ * W_;

        k_prep<<<(2 * L_ * K1_ + NCOL * L_) / 256, 256, 0, stream>>>(bgb, fgb, bgcol, fgcol, colsT);

        dim3 g1(32, 32);
        k_gemm1_mfma<<<g1, 256, 0, stream>>>(bgcol, fgcol, denom_inv + b * L_, scores, Y);
        k_pass1_edge<<<2048, 256, 0, stream>>>(scores, Y);

        k_soft3<<<4096, 256, 0, stream>>>(Y, maskedf + b * L_, softT, pml, pz);
        k_zr<<<4096, 256, 0, stream>>>(pml, pz, softT);

        dim3 g5(8, 32, 2);
        k_gemm2_mfma<<<g5, 256, 0, stream>>>(softT, colsT, patchP);
        k_col2im<<<(C_ * H_ * W_) / 256, 256, 0, stream>>>(patchP, out + (size_t)b * C_ * H_ * W_);
    }
}